// Round 2
// baseline (1211.059 us; speedup 1.0000x reference)
//
#include <hip/hip_runtime.h>

typedef unsigned short u16;
typedef __attribute__((ext_vector_type(8))) short bf16x8;
typedef __attribute__((ext_vector_type(4))) float f32x4;

#define S_CTX 2048
#define DMODEL 2048

__device__ __forceinline__ float bf2f(u16 u) {
  union { unsigned int i; float f; } v; v.i = ((unsigned int)u) << 16; return v.f;
}
__device__ __forceinline__ u16 f2bf(float f) {
  union { float f; unsigned int i; } v; v.f = f;
  unsigned int r = v.i + 0x7FFFu + ((v.i >> 16) & 1u);
  return (u16)(r >> 16);
}

// f32 -> (hi, lo) bf16 split: x ~= hi + lo, |lo| <= 2^-9 |x|, residual err ~2^-18
__global__ void split_kernel(const float* __restrict__ src, u16* __restrict__ hi,
                             u16* __restrict__ lo, int n) {
  int i = blockIdx.x * 256 + threadIdx.x;
  if (i >= n) return;
  float v = src[i];
  u16 h = f2bf(v);
  hi[i] = h;
  lo[i] = f2bf(v - bf2f(h));
}

// C[M,N] = (Ah+Al)[M,K] * (Bh+Bl)[N,K]^T via 3-term split MFMA (hh + hl + lh).
// Output: if Cf != nullptr -> f32; else -> split bf16 pair (Ch, Cl).
__global__ __launch_bounds__(256) void gemm3_bt(
    const u16* __restrict__ Ah, const u16* __restrict__ Al,
    const u16* __restrict__ Bth, const u16* __restrict__ Btl,
    float* __restrict__ Cf, u16* __restrict__ Ch, u16* __restrict__ Cl,
    int M, int N, int K) {
  __shared__ u16 sAh[128 * 32];
  __shared__ u16 sAl[128 * 32];
  __shared__ u16 sBh[128 * 32];
  __shared__ u16 sBl[128 * 32];
  const int m0 = blockIdx.y << 7, n0 = blockIdx.x << 7;
  const int tid = threadIdx.x;
  const int w = tid >> 6, lane = tid & 63;
  const int quad = lane >> 4, l16 = lane & 15;
  const int wm = (w >> 1) << 6, wn = (w & 1) << 6;

  f32x4 acc[4][4];
#pragma unroll
  for (int i = 0; i < 4; ++i)
#pragma unroll
    for (int n = 0; n < 4; ++n) acc[i][n] = (f32x4){0.f, 0.f, 0.f, 0.f};

  for (int k0 = 0; k0 < K; k0 += 32) {
    __syncthreads();
#pragma unroll
    for (int j = 0; j < 2; ++j) {
      int c = j * 256 + tid;                 // 0..511
      int row = c >> 2, col = (c & 3) << 3;  // [128][32]
      size_t ga = (size_t)(m0 + row) * K + k0 + col;
      size_t gb = (size_t)(n0 + row) * K + k0 + col;
      *(bf16x8*)&sAh[row * 32 + col] = *(const bf16x8*)(Ah + ga);
      *(bf16x8*)&sAl[row * 32 + col] = *(const bf16x8*)(Al + ga);
      *(bf16x8*)&sBh[row * 32 + col] = *(const bf16x8*)(Bth + gb);
      *(bf16x8*)&sBl[row * 32 + col] = *(const bf16x8*)(Btl + gb);
    }
    __syncthreads();
    bf16x8 ah[4], al[4], bh[4], bl[4];
#pragma unroll
    for (int i = 0; i < 4; ++i) {
      int o = (wm + i * 16 + l16) * 32 + quad * 8;
      ah[i] = *(const bf16x8*)&sAh[o];
      al[i] = *(const bf16x8*)&sAl[o];
    }
#pragma unroll
    for (int n = 0; n < 4; ++n) {
      int o = (wn + n * 16 + l16) * 32 + quad * 8;
      bh[n] = *(const bf16x8*)&sBh[o];
      bl[n] = *(const bf16x8*)&sBl[o];
    }
#pragma unroll
    for (int i = 0; i < 4; ++i)
#pragma unroll
      for (int n = 0; n < 4; ++n) {
        acc[i][n] = __builtin_amdgcn_mfma_f32_16x16x32_bf16(ah[i], bh[n], acc[i][n], 0, 0, 0);
        acc[i][n] = __builtin_amdgcn_mfma_f32_16x16x32_bf16(ah[i], bl[n], acc[i][n], 0, 0, 0);
        acc[i][n] = __builtin_amdgcn_mfma_f32_16x16x32_bf16(al[i], bh[n], acc[i][n], 0, 0, 0);
      }
  }
  // C/D layout: row=(lane>>4)*4+r, col=lane&15
#pragma unroll
  for (int i = 0; i < 4; ++i)
#pragma unroll
    for (int n = 0; n < 4; ++n)
#pragma unroll
      for (int r = 0; r < 4; ++r) {
        int row = m0 + wm + i * 16 + quad * 4 + r;
        int col = n0 + wn + n * 16 + l16;
        float v = acc[i][n][r];
        size_t o = (size_t)row * N + col;
        if (Cf) {
          Cf[o] = v;
        } else {
          u16 h = f2bf(v);
          Ch[o] = h;
          Cl[o] = f2bf(v - bf2f(h));
        }
      }
}

// RoPE on split q,k in place: recombine f32, rotate, re-split.
// layout [B,S,NH,HD]=[2,2048,16,128]; cos/sin f32 [4096,128], cos[s,d]==cos[s,d+64]
__global__ void rope_split(u16* __restrict__ qh, u16* __restrict__ ql,
                           u16* __restrict__ kh, u16* __restrict__ kl,
                           const float* __restrict__ cosT, const float* __restrict__ sinT) {
  int idx = blockIdx.x * 256 + threadIdx.x;  // 23 bits
  int d  = idx & 63;
  int hh = (idx >> 6) & 15;
  int s  = (idx >> 10) & 2047;
  int b  = (idx >> 21) & 1;
  int isk = (idx >> 22) & 1;
  u16* th = isk ? kh : qh;
  u16* tl = isk ? kl : ql;
  size_t base = (size_t)(b * 2048 + s) * DMODEL + hh * 128;
  float c  = cosT[s * 128 + d];
  float sn = sinT[s * 128 + d];
  float x1 = bf2f(th[base + d]) + bf2f(tl[base + d]);
  float x2 = bf2f(th[base + d + 64]) + bf2f(tl[base + d + 64]);
  float o1 = x1 * c - x2 * sn;
  float o2 = x2 * c + x1 * sn;
  u16 h1 = f2bf(o1);
  th[base + d] = h1;
  tl[base + d] = f2bf(o1 - bf2f(h1));
  u16 h2 = f2bf(o2);
  th[base + d + 64] = h2;
  tl[base + d + 64] = f2bf(o2 - bf2f(h2));
}

// Flash attention, causal, scores scaled by *sqrt(128)* (reference multiplies).
// 3-term split QK^T (qh*kh + qh*kl + ql*kh), f32 online softmax, single-bf16 PV.
// Grid: (qt=0..31, bh=0..31). Block = 256 = 4 waves; BQ=64 (16 q-rows/wave), BK=64.
// Output ctx written as split bf16 pair (Ch, Cl).
__global__ __launch_bounds__(256) void attn3_kernel(
    const u16* __restrict__ Qh, const u16* __restrict__ Ql,
    const u16* __restrict__ Kh, const u16* __restrict__ Kl,
    const u16* __restrict__ Vh, u16* __restrict__ Ch, u16* __restrict__ Cl) {
  const int qt = blockIdx.x;
  const int b = blockIdx.y >> 4, h = blockIdx.y & 15;
  const int tid = threadIdx.x;
  const int w = tid >> 6, lane = tid & 63;
  const int quad = lane >> 4, l16 = lane & 15;

  __shared__ u16 sKh[64 * 128];  // K-tile hi, row-major [k][d]
  __shared__ u16 sKl[64 * 128];  // K-tile lo
  __shared__ u16 sV[128 * 64];   // V^T swizzled: (k,n)->n*64+(((k>>3)^((n>>3)&7))<<3)+(k&7)
  __shared__ u16 sP[4][16 * 72]; // per-wave P round-trip

  const size_t bhbase = (size_t)b * S_CTX * DMODEL + (size_t)h * 128;

  // Q fragments (A-operand: m=l16, k=quad*8+j); wave w owns q-rows qt*64+w*16+[0,16)
  const int qrow = qt * 64 + w * 16 + l16;
  const size_t qoff = bhbase + (size_t)qrow * DMODEL;
  bf16x8 qfh[4], qfl[4];
#pragma unroll
  for (int c = 0; c < 4; ++c) {
    qfh[c] = *(const bf16x8*)(Qh + qoff + c * 32 + quad * 8);
    qfl[c] = *(const bf16x8*)(Ql + qoff + c * 32 + quad * 8);
  }

  f32x4 oacc[8];
#pragma unroll
  for (int d = 0; d < 8; ++d) oacc[d] = (f32x4){0.f, 0.f, 0.f, 0.f};
  float m_r[4] = {-INFINITY, -INFINITY, -INFINITY, -INFINITY};
  float l_r[4] = {0.f, 0.f, 0.f, 0.f};

  const float scale = 11.313708498984761f;  // sqrt(128)

  for (int kt = 0; kt <= qt; ++kt) {
    __syncthreads();
    // stage K hi/lo tiles [64][128]
#pragma unroll
    for (int j = 0; j < 4; ++j) {
      int c = j * 256 + tid;
      int row = c >> 4, col = (c & 15) << 3;
      size_t g = bhbase + (size_t)(kt * 64 + row) * DMODEL + col;
      *(bf16x8*)&sKh[row * 128 + col] = *(const bf16x8*)(Kh + g);
      *(bf16x8*)&sKl[row * 128 + col] = *(const bf16x8*)(Kl + g);
    }
    // stage V transposed (swizzled scatter)
#pragma unroll
    for (int j = 0; j < 4; ++j) {
      int c = j * 256 + tid;
      int row = c >> 4, col = (c & 15) << 3;
      bf16x8 val = *(const bf16x8*)(Vh + bhbase + (size_t)(kt * 64 + row) * DMODEL + col);
#pragma unroll
      for (int e = 0; e < 8; ++e) {
        int n = col + e;
        int ch = (row >> 3) ^ ((n >> 3) & 7);
        sV[n * 64 + (ch << 3) + (row & 7)] = (u16)val[e];
      }
    }
    __syncthreads();

    // S = Q.K^T, 3-term split (16 q-rows x 64 k-cols per wave)
    f32x4 sacc[4];
#pragma unroll
    for (int n = 0; n < 4; ++n) sacc[n] = (f32x4){0.f, 0.f, 0.f, 0.f};
#pragma unroll
    for (int n = 0; n < 4; ++n)
#pragma unroll
      for (int c = 0; c < 4; ++c) {
        int o = (n * 16 + l16) * 128 + c * 32 + quad * 8;
        bf16x8 kfh = *(const bf16x8*)&sKh[o];
        bf16x8 kfl = *(const bf16x8*)&sKl[o];
        sacc[n] = __builtin_amdgcn_mfma_f32_16x16x32_bf16(qfh[c], kfh, sacc[n], 0, 0, 0);
        sacc[n] = __builtin_amdgcn_mfma_f32_16x16x32_bf16(qfh[c], kfl, sacc[n], 0, 0, 0);
        sacc[n] = __builtin_amdgcn_mfma_f32_16x16x32_bf16(qfl[c], kfh, sacc[n], 0, 0, 0);
      }

    // scale + causal mask + online softmax (C-layout row = quad*4+r, col = n*16+l16)
    float pm[4][4];
    float rowmax[4] = {-INFINITY, -INFINITY, -INFINITY, -INFINITY};
#pragma unroll
    for (int n = 0; n < 4; ++n)
#pragma unroll
      for (int r = 0; r < 4; ++r) {
        float sc = sacc[n][r] * scale;
        int qi = qt * 64 + w * 16 + quad * 4 + r;
        int ki = kt * 64 + n * 16 + l16;
        if (ki > qi) sc = -INFINITY;
        pm[n][r] = sc;
        rowmax[r] = fmaxf(rowmax[r], sc);
      }
#pragma unroll
    for (int off = 1; off < 16; off <<= 1)
#pragma unroll
      for (int r = 0; r < 4; ++r)
        rowmax[r] = fmaxf(rowmax[r], __shfl_xor(rowmax[r], off, 64));

    float alphav[4];
#pragma unroll
    for (int r = 0; r < 4; ++r) {
      float mnew = fmaxf(m_r[r], rowmax[r]);
      alphav[r] = __expf(m_r[r] - mnew);  // expf(-inf)=0 on first tile
      m_r[r] = mnew;
      l_r[r] *= alphav[r];
    }
    float rowsum[4] = {0.f, 0.f, 0.f, 0.f};
#pragma unroll
    for (int n = 0; n < 4; ++n)
#pragma unroll
      for (int r = 0; r < 4; ++r) {
        float p = __expf(pm[n][r] - m_r[r]);
        pm[n][r] = p;
        rowsum[r] += p;
      }
#pragma unroll
    for (int off = 1; off < 16; off <<= 1)
#pragma unroll
      for (int r = 0; r < 4; ++r) rowsum[r] += __shfl_xor(rowsum[r], off, 64);
#pragma unroll
    for (int r = 0; r < 4; ++r) l_r[r] += rowsum[r];

#pragma unroll
    for (int d = 0; d < 8; ++d)
#pragma unroll
      for (int r = 0; r < 4; ++r) oacc[d][r] *= alphav[r];

    // P (C-layout) -> LDS -> A-layout; per-wave region
#pragma unroll
    for (int n = 0; n < 4; ++n)
#pragma unroll
      for (int r = 0; r < 4; ++r)
        sP[w][(quad * 4 + r) * 72 + n * 16 + l16] = f2bf(pm[n][r]);

    // O += P.V
#pragma unroll
    for (int c = 0; c < 2; ++c) {
      bf16x8 pf = *(const bf16x8*)&sP[w][l16 * 72 + c * 32 + quad * 8];
#pragma unroll
      for (int d = 0; d < 8; ++d) {
        int nrow = d * 16 + l16;
        int ch = ((c << 2) + quad) ^ ((nrow >> 3) & 7);
        bf16x8 vf = *(const bf16x8*)&sV[nrow * 64 + (ch << 3)];
        oacc[d] = __builtin_amdgcn_mfma_f32_16x16x32_bf16(pf, vf, oacc[d], 0, 0, 0);
      }
    }
  }

  float invl[4];
#pragma unroll
  for (int r = 0; r < 4; ++r) invl[r] = 1.f / l_r[r];
#pragma unroll
  for (int d = 0; d < 8; ++d)
#pragma unroll
    for (int r = 0; r < 4; ++r) {
      int row = qt * 64 + w * 16 + quad * 4 + r;
      size_t o = bhbase + (size_t)row * DMODEL + d * 16 + l16;
      float v = oacc[d][r] * invl[r];
      u16 hh = f2bf(v);
      Ch[o] = hh;
      Cl[o] = f2bf(v - bf2f(hh));
    }
}

extern "C" void kernel_launch(void* const* d_in, const int* in_sizes, int n_in,
                              void* d_out, int out_size, void* d_ws, size_t ws_size,
                              hipStream_t stream) {
  const float* x    = (const float*)d_in[0];
  const float* Wq   = (const float*)d_in[1];
  const float* Wk   = (const float*)d_in[2];
  const float* Wv   = (const float*)d_in[3];
  const float* Wo   = (const float*)d_in[4];
  const float* cosT = (const float*)d_in[5];
  const float* sinT = (const float*)d_in[6];
  float* out = (float*)d_out;

  const size_t NX = 8388608;   // 2*2048*2048
  const size_t NW = 4194304;   // 2048*2048
  u16* p = (u16*)d_ws;
  u16* xh  = p; p += NX;  u16* xl  = p; p += NX;
  u16* Wqh = p; p += NW;  u16* Wql = p; p += NW;
  u16* Wkh = p; p += NW;  u16* Wkl = p; p += NW;
  u16* Wvh = p; p += NW;  u16* Wvl = p; p += NW;
  u16* Woh = p; p += NW;  u16* Wol = p; p += NW;
  u16* qh  = p; p += NX;  u16* ql  = p; p += NX;
  u16* kh  = p; p += NX;  u16* kl  = p; p += NX;
  u16* vh  = p; p += NX;  u16* vl  = p; p += NX;
  u16* ch  = p; p += NX;  u16* cl  = p; p += NX;
  // total 224 MiB of d_ws

  split_kernel<<<NX / 256, 256, 0, stream>>>(x, xh, xl, (int)NX);
  split_kernel<<<NW / 256, 256, 0, stream>>>(Wq, Wqh, Wql, (int)NW);
  split_kernel<<<NW / 256, 256, 0, stream>>>(Wk, Wkh, Wkl, (int)NW);
  split_kernel<<<NW / 256, 256, 0, stream>>>(Wv, Wvh, Wvl, (int)NW);
  split_kernel<<<NW / 256, 256, 0, stream>>>(Wo, Woh, Wol, (int)NW);

  dim3 ggrid(DMODEL / 128, 4096 / 128);  // (16, 32)
  gemm3_bt<<<ggrid, 256, 0, stream>>>(xh, xl, Wqh, Wql, nullptr, qh, ql, 4096, DMODEL, DMODEL);
  gemm3_bt<<<ggrid, 256, 0, stream>>>(xh, xl, Wkh, Wkl, nullptr, kh, kl, 4096, DMODEL, DMODEL);
  gemm3_bt<<<ggrid, 256, 0, stream>>>(xh, xl, Wvh, Wvl, nullptr, vh, vl, 4096, DMODEL, DMODEL);

  rope_split<<<NX / 256, 256, 0, stream>>>(qh, ql, kh, kl, cosT, sinT);

  attn3_kernel<<<dim3(32, 32), 256, 0, stream>>>(qh, ql, kh, kl, vh, ch, cl);

  gemm3_bt<<<ggrid, 256, 0, stream>>>(ch, cl, Woh, Wol, out, nullptr, nullptr, 4096, DMODEL, DMODEL);
}

// Round 3
// 817.206 us; speedup vs baseline: 1.4820x; 1.4820x over previous
//
#include <hip/hip_runtime.h>

typedef unsigned short u16;
typedef __attribute__((ext_vector_type(8))) short bf16x8;
typedef __attribute__((ext_vector_type(4))) float f32x4;

#define S_CTX 2048
#define DMODEL 2048

__device__ __forceinline__ float bf2f(u16 u) {
  union { unsigned int i; float f; } v; v.i = ((unsigned int)u) << 16; return v.f;
}
__device__ __forceinline__ u16 f2bf(float f) {
  union { float f; unsigned int i; } v; v.f = f;
  unsigned int r = v.i + 0x7FFFu + ((v.i >> 16) & 1u);
  return (u16)(r >> 16);
}
__device__ __forceinline__ void gload16(const u16* g, u16* l) {
  __builtin_amdgcn_global_load_lds(
      (const __attribute__((address_space(1))) unsigned int*)g,
      (__attribute__((address_space(3))) unsigned int*)l, 16, 0, 0);
}

// f32 -> (hi, lo) bf16 split
__global__ void split_kernel(const float* __restrict__ src, u16* __restrict__ hi,
                             u16* __restrict__ lo, int n) {
  int i = blockIdx.x * 256 + threadIdx.x;
  if (i >= n) return;
  float v = src[i];
  u16 h = f2bf(v);
  hi[i] = h;
  lo[i] = f2bf(v - bf2f(h));
}

// C[M,N] = (Ah+Al)*(Bth+Btl)^T, 3-term split MFMA, m97-style global_load_lds staging.
// mode 0: f32 -> Cf ; mode 1: split bf16 -> (Ch, Cl) ; mode 2: V^T bf16 -> Ch
// (mode 2 layout: [b][h][d][s] i.e. ((row>>11)*16 + col>>7)*128 + (col&127))*2048 + (row&2047))
__global__ __launch_bounds__(256) void gemm3_bt(
    const u16* __restrict__ Ah, const u16* __restrict__ Al,
    const u16* __restrict__ Bth, const u16* __restrict__ Btl,
    float* __restrict__ Cf, u16* __restrict__ Ch, u16* __restrict__ Cl,
    int M, int N, int K, int mode) {
  __shared__ u16 sAh[128 * 32];
  __shared__ u16 sAl[128 * 32];
  __shared__ u16 sBh[128 * 32];
  __shared__ u16 sBl[128 * 32];
  const int m0 = blockIdx.y << 7, n0 = blockIdx.x << 7;
  const int tid = threadIdx.x;
  const int w = tid >> 6, lane = tid & 63;
  const int quad = lane >> 4, l16 = lane & 15;
  const int wm = (w >> 1) << 6, wn = (w & 1) << 6;
  const int lrow = lane >> 2, lcol = (lane & 3) << 3;  // global_load_lds mapping

  f32x4 acc[4][4];
#pragma unroll
  for (int i = 0; i < 4; ++i)
#pragma unroll
    for (int n = 0; n < 4; ++n) acc[i][n] = (f32x4){0.f, 0.f, 0.f, 0.f};

  for (int k0 = 0; k0 < K; k0 += 32) {
    __syncthreads();
#pragma unroll
    for (int j = 0; j < 2; ++j) {
      int r = w * 32 + j * 16 + lrow;           // tile row this lane fetches
      int lb = (w * 32 + j * 16) * 32;          // wave-uniform LDS base (u16 idx)
      size_t ga = (size_t)(m0 + r) * K + k0 + lcol;
      size_t gb = (size_t)(n0 + r) * K + k0 + lcol;
      gload16(Ah + ga, &sAh[lb]);
      gload16(Al + ga, &sAl[lb]);
      gload16(Bth + gb, &sBh[lb]);
      gload16(Btl + gb, &sBl[lb]);
    }
    __syncthreads();
    bf16x8 ah[4], al[4], bh[4], bl[4];
#pragma unroll
    for (int i = 0; i < 4; ++i) {
      int o = (wm + i * 16 + l16) * 32 + quad * 8;
      ah[i] = *(const bf16x8*)&sAh[o];
      al[i] = *(const bf16x8*)&sAl[o];
    }
#pragma unroll
    for (int n = 0; n < 4; ++n) {
      int o = (wn + n * 16 + l16) * 32 + quad * 8;
      bh[n] = *(const bf16x8*)&sBh[o];
      bl[n] = *(const bf16x8*)&sBl[o];
    }
#pragma unroll
    for (int i = 0; i < 4; ++i)
#pragma unroll
      for (int n = 0; n < 4; ++n) {
        acc[i][n] = __builtin_amdgcn_mfma_f32_16x16x32_bf16(ah[i], bh[n], acc[i][n], 0, 0, 0);
        acc[i][n] = __builtin_amdgcn_mfma_f32_16x16x32_bf16(ah[i], bl[n], acc[i][n], 0, 0, 0);
        acc[i][n] = __builtin_amdgcn_mfma_f32_16x16x32_bf16(al[i], bh[n], acc[i][n], 0, 0, 0);
      }
  }
  // epilogue: C/D layout row=(lane>>4)*4+r, col=lane&15
#pragma unroll
  for (int i = 0; i < 4; ++i)
#pragma unroll
    for (int n = 0; n < 4; ++n) {
      int row0 = m0 + wm + i * 16 + quad * 4;
      int col = n0 + wn + n * 16 + l16;
      if (mode == 0) {
#pragma unroll
        for (int r = 0; r < 4; ++r) Cf[(size_t)(row0 + r) * N + col] = acc[i][n][r];
      } else if (mode == 1) {
#pragma unroll
        for (int r = 0; r < 4; ++r) {
          float v = acc[i][n][r];
          size_t o = (size_t)(row0 + r) * N + col;
          u16 h = f2bf(v);
          Ch[o] = h;
          Cl[o] = f2bf(v - bf2f(h));
        }
      } else {
        int brow = row0 >> 11, s0 = row0 & 2047;
        int hh = col >> 7, d = col & 127;
        ushort4 pk;
        pk.x = f2bf(acc[i][n][0]);
        pk.y = f2bf(acc[i][n][1]);
        pk.z = f2bf(acc[i][n][2]);
        pk.w = f2bf(acc[i][n][3]);
        *(ushort4*)(Ch + ((size_t)(brow * 16 + hh) * 128 + d) * 2048 + s0) = pk;
      }
    }
}

// RoPE on split q,k in place; q additionally pre-scaled by sqrt(128)
// (the reference MULTIPLIES scores by sqrt(128)).
__global__ void rope_split(u16* __restrict__ qh, u16* __restrict__ ql,
                           u16* __restrict__ kh, u16* __restrict__ kl,
                           const float* __restrict__ cosT, const float* __restrict__ sinT) {
  int idx = blockIdx.x * 256 + threadIdx.x;  // 23 bits
  int d  = idx & 63;
  int hh = (idx >> 6) & 15;
  int s  = (idx >> 10) & 2047;
  int b  = (idx >> 21) & 1;
  int isk = (idx >> 22) & 1;
  u16* th = isk ? kh : qh;
  u16* tl = isk ? kl : ql;
  size_t base = (size_t)(b * 2048 + s) * DMODEL + hh * 128;
  float c  = cosT[s * 128 + d];
  float sn = sinT[s * 128 + d];
  float x1 = bf2f(th[base + d]) + bf2f(tl[base + d]);
  float x2 = bf2f(th[base + d + 64]) + bf2f(tl[base + d + 64]);
  float o1 = x1 * c - x2 * sn;
  float o2 = x2 * c + x1 * sn;
  if (!isk) { o1 *= 11.313708498984761f; o2 *= 11.313708498984761f; }
  u16 h1 = f2bf(o1);
  th[base + d] = h1;
  tl[base + d] = f2bf(o1 - bf2f(h1));
  u16 h2 = f2bf(o2);
  th[base + d + 64] = h2;
  tl[base + d + 64] = f2bf(o2 - bf2f(h2));
}

// Flash attention, causal. q pre-scaled by sqrt(128). 3-term split QK^T,
// f32 online softmax, single-bf16 PV with V^T staged from global [b][h][d][s].
// Register prefetch of tile kt+1 overlaps compute on kt. qt runs descending.
__global__ __launch_bounds__(256) void attn3_kernel(
    const u16* __restrict__ Qh, const u16* __restrict__ Ql,
    const u16* __restrict__ Kh, const u16* __restrict__ Kl,
    const u16* __restrict__ VT, u16* __restrict__ Ch, u16* __restrict__ Cl) {
  const int qt = gridDim.x - 1 - blockIdx.x;  // big blocks first
  const int bh = blockIdx.y;
  const int b = bh >> 4, h = bh & 15;
  const int tid = threadIdx.x;
  const int w = tid >> 6, lane = tid & 63;
  const int quad = lane >> 4, l16 = lane & 15;

  __shared__ u16 sKh[64 * 136];   // K hi, rows padded 128->136 (2-way banks)
  __shared__ u16 sKl[64 * 136];   // K lo
  __shared__ u16 sVt[128 * 72];   // V^T tile [d][k], rows padded 64->72
  __shared__ u16 sP[4][16 * 72];  // per-wave P round-trip

  const size_t bhbase = (size_t)b * S_CTX * DMODEL + (size_t)h * 128;
  const size_t vtbase = (size_t)bh * 128 * 2048;

  // staging coords (4 chunks per thread per array)
  int kr[4], kc[4], vr[4], vc[4];
#pragma unroll
  for (int j = 0; j < 4; ++j) {
    int c = j * 256 + tid;
    kr[j] = c >> 4; kc[j] = (c & 15) << 3;
    vr[j] = c >> 3; vc[j] = (c & 7) << 3;
  }

  // Q fragments (A-operand: m=l16, k=quad*8+j); wave w owns q-rows qt*64+w*16+[0,16)
  const int qrow = qt * 64 + w * 16 + l16;
  const size_t qoff = bhbase + (size_t)qrow * DMODEL;
  bf16x8 qfh[4], qfl[4];
#pragma unroll
  for (int c = 0; c < 4; ++c) {
    qfh[c] = *(const bf16x8*)(Qh + qoff + c * 32 + quad * 8);
    qfl[c] = *(const bf16x8*)(Ql + qoff + c * 32 + quad * 8);
  }

  f32x4 oacc[8];
#pragma unroll
  for (int d = 0; d < 8; ++d) oacc[d] = (f32x4){0.f, 0.f, 0.f, 0.f};
  float m_r[4] = {-INFINITY, -INFINITY, -INFINITY, -INFINITY};
  float l_r[4] = {0.f, 0.f, 0.f, 0.f};

  // prefetch registers
  bf16x8 rkh[4], rkl[4], rvt[4];
#pragma unroll
  for (int j = 0; j < 4; ++j) {
    size_t g = bhbase + (size_t)(0 * 64 + kr[j]) * DMODEL + kc[j];
    rkh[j] = *(const bf16x8*)(Kh + g);
    rkl[j] = *(const bf16x8*)(Kl + g);
    rvt[j] = *(const bf16x8*)(VT + vtbase + (size_t)vr[j] * 2048 + 0 * 64 + vc[j]);
  }

  for (int kt = 0; kt <= qt; ++kt) {
    __syncthreads();  // previous compute done reading LDS
#pragma unroll
    for (int j = 0; j < 4; ++j) {
      *(bf16x8*)&sKh[kr[j] * 136 + kc[j]] = rkh[j];
      *(bf16x8*)&sKl[kr[j] * 136 + kc[j]] = rkl[j];
      *(bf16x8*)&sVt[vr[j] * 72 + vc[j]] = rvt[j];
    }
    __syncthreads();
    if (kt < qt) {  // prefetch next tile while computing this one
#pragma unroll
      for (int j = 0; j < 4; ++j) {
        size_t g = bhbase + (size_t)((kt + 1) * 64 + kr[j]) * DMODEL + kc[j];
        rkh[j] = *(const bf16x8*)(Kh + g);
        rkl[j] = *(const bf16x8*)(Kl + g);
        rvt[j] = *(const bf16x8*)(VT + vtbase + (size_t)vr[j] * 2048 + (kt + 1) * 64 + vc[j]);
      }
    }

    // S = Q.K^T, 3-term split
    f32x4 sacc[4];
#pragma unroll
    for (int n = 0; n < 4; ++n) sacc[n] = (f32x4){0.f, 0.f, 0.f, 0.f};
#pragma unroll
    for (int n = 0; n < 4; ++n)
#pragma unroll
      for (int c = 0; c < 4; ++c) {
        int o = (n * 16 + l16) * 136 + c * 32 + quad * 8;
        bf16x8 kfh = *(const bf16x8*)&sKh[o];
        bf16x8 kfl = *(const bf16x8*)&sKl[o];
        sacc[n] = __builtin_amdgcn_mfma_f32_16x16x32_bf16(qfh[c], kfh, sacc[n], 0, 0, 0);
        sacc[n] = __builtin_amdgcn_mfma_f32_16x16x32_bf16(qfh[c], kfl, sacc[n], 0, 0, 0);
        sacc[n] = __builtin_amdgcn_mfma_f32_16x16x32_bf16(qfl[c], kfh, sacc[n], 0, 0, 0);
      }

    // causal mask only on the diagonal tile
    float pm[4][4];
    float rowmax[4] = {-INFINITY, -INFINITY, -INFINITY, -INFINITY};
#pragma unroll
    for (int n = 0; n < 4; ++n)
#pragma unroll
      for (int r = 0; r < 4; ++r) {
        float sc = sacc[n][r];
        if (kt == qt) {
          int qi = w * 16 + quad * 4 + r;       // within-tile q index
          int ki = n * 16 + l16;                // within-tile k index
          if (ki > qi) sc = -INFINITY;
        }
        pm[n][r] = sc;
        rowmax[r] = fmaxf(rowmax[r], sc);
      }
#pragma unroll
    for (int off = 1; off < 16; off <<= 1)
#pragma unroll
      for (int r = 0; r < 4; ++r)
        rowmax[r] = fmaxf(rowmax[r], __shfl_xor(rowmax[r], off, 64));

    float alphav[4];
#pragma unroll
    for (int r = 0; r < 4; ++r) {
      float mnew = fmaxf(m_r[r], rowmax[r]);
      alphav[r] = __expf(m_r[r] - mnew);
      m_r[r] = mnew;
      l_r[r] *= alphav[r];
    }
    float rowsum[4] = {0.f, 0.f, 0.f, 0.f};
#pragma unroll
    for (int n = 0; n < 4; ++n)
#pragma unroll
      for (int r = 0; r < 4; ++r) {
        float p = __expf(pm[n][r] - m_r[r]);
        pm[n][r] = p;
        rowsum[r] += p;
      }
#pragma unroll
    for (int off = 1; off < 16; off <<= 1)
#pragma unroll
      for (int r = 0; r < 4; ++r) rowsum[r] += __shfl_xor(rowsum[r], off, 64);
#pragma unroll
    for (int r = 0; r < 4; ++r) l_r[r] += rowsum[r];

#pragma unroll
    for (int d = 0; d < 8; ++d)
#pragma unroll
      for (int r = 0; r < 4; ++r) oacc[d][r] *= alphav[r];

    // P (C-layout) -> LDS -> A-layout; per-wave region (no cross-wave sync)
#pragma unroll
    for (int n = 0; n < 4; ++n)
#pragma unroll
      for (int r = 0; r < 4; ++r)
        sP[w][(quad * 4 + r) * 72 + n * 16 + l16] = f2bf(pm[n][r]);

    // O += P.V  (B-operand = V^T fragments, contiguous reads)
#pragma unroll
    for (int c = 0; c < 2; ++c) {
      bf16x8 pf = *(const bf16x8*)&sP[w][l16 * 72 + c * 32 + quad * 8];
#pragma unroll
      for (int d = 0; d < 8; ++d) {
        bf16x8 vf = *(const bf16x8*)&sVt[(d * 16 + l16) * 72 + c * 32 + quad * 8];
        oacc[d] = __builtin_amdgcn_mfma_f32_16x16x32_bf16(pf, vf, oacc[d], 0, 0, 0);
      }
    }
  }

  float invl[4];
#pragma unroll
  for (int r = 0; r < 4; ++r) invl[r] = 1.f / l_r[r];
#pragma unroll
  for (int d = 0; d < 8; ++d)
#pragma unroll
    for (int r = 0; r < 4; ++r) {
      int row = qt * 64 + w * 16 + quad * 4 + r;
      size_t o = bhbase + (size_t)row * DMODEL + d * 16 + l16;
      float v = oacc[d][r] * invl[r];
      u16 hh = f2bf(v);
      Ch[o] = hh;
      Cl[o] = f2bf(v - bf2f(hh));
    }
}

extern "C" void kernel_launch(void* const* d_in, const int* in_sizes, int n_in,
                              void* d_out, int out_size, void* d_ws, size_t ws_size,
                              hipStream_t stream) {
  const float* x    = (const float*)d_in[0];
  const float* Wq   = (const float*)d_in[1];
  const float* Wk   = (const float*)d_in[2];
  const float* Wv   = (const float*)d_in[3];
  const float* Wo   = (const float*)d_in[4];
  const float* cosT = (const float*)d_in[5];
  const float* sinT = (const float*)d_in[6];
  float* out = (float*)d_out;

  const size_t NX = 8388608;   // 2*2048*2048
  const size_t NW = 4194304;   // 2048*2048
  u16* p = (u16*)d_ws;
  u16* xh  = p; p += NX;  u16* xl  = p; p += NX;
  u16* Wqh = p; p += NW;  u16* Wql = p; p += NW;
  u16* Wkh = p; p += NW;  u16* Wkl = p; p += NW;
  u16* Wvh = p; p += NW;  u16* Wvl = p; p += NW;
  u16* Woh = p; p += NW;  u16* Wol = p; p += NW;
  u16* qh  = p; p += NX;  u16* ql  = p; p += NX;
  u16* kh  = p; p += NX;  u16* kl  = p; p += NX;
  u16* vt  = p; p += NX;
  u16* ch  = p; p += NX;  u16* cl  = p; p += NX;
  // total ~218 MiB of d_ws

  split_kernel<<<NX / 256, 256, 0, stream>>>(x, xh, xl, (int)NX);
  split_kernel<<<NW / 256, 256, 0, stream>>>(Wq, Wqh, Wql, (int)NW);
  split_kernel<<<NW / 256, 256, 0, stream>>>(Wk, Wkh, Wkl, (int)NW);
  split_kernel<<<NW / 256, 256, 0, stream>>>(Wv, Wvh, Wvl, (int)NW);
  split_kernel<<<NW / 256, 256, 0, stream>>>(Wo, Woh, Wol, (int)NW);

  dim3 ggrid(DMODEL / 128, 4096 / 128);  // (16, 32)
  gemm3_bt<<<ggrid, 256, 0, stream>>>(xh, xl, Wqh, Wql, nullptr, qh, ql, 4096, DMODEL, DMODEL, 1);
  gemm3_bt<<<ggrid, 256, 0, stream>>>(xh, xl, Wkh, Wkl, nullptr, kh, kl, 4096, DMODEL, DMODEL, 1);
  gemm3_bt<<<ggrid, 256, 0, stream>>>(xh, xl, Wvh, Wvl, nullptr, vt, nullptr, 4096, DMODEL, DMODEL, 2);

  rope_split<<<NX / 256, 256, 0, stream>>>(qh, ql, kh, kl, cosT, sinT);

  attn3_kernel<<<dim3(32, 32), 256, 0, stream>>>(qh, ql, kh, kl, vt, ch, cl);

  gemm3_bt<<<ggrid, 256, 0, stream>>>(ch, cl, Woh, Wol, out, nullptr, nullptr, 4096, DMODEL, DMODEL, 0);
}

// Round 4
// 739.082 us; speedup vs baseline: 1.6386x; 1.1057x over previous
//
#include <hip/hip_runtime.h>

typedef unsigned short u16;
typedef __attribute__((ext_vector_type(8))) short bf16x8;
typedef __attribute__((ext_vector_type(4))) float f32x4;

#define S_CTX 2048
#define DMODEL 2048

__device__ __forceinline__ float bf2f(u16 u) {
  union { unsigned int i; float f; } v; v.i = ((unsigned int)u) << 16; return v.f;
}
__device__ __forceinline__ u16 f2bf(float f) {
  union { float f; unsigned int i; } v; v.f = f;
  unsigned int r = v.i + 0x7FFFu + ((v.i >> 16) & 1u);
  return (u16)(r >> 16);
}
__device__ __forceinline__ void gload16(const u16* g, u16* l) {
  __builtin_amdgcn_global_load_lds(
      (const __attribute__((address_space(1))) unsigned int*)g,
      (__attribute__((address_space(3))) unsigned int*)l, 16, 0, 0);
}

// f32 -> (hi, lo) bf16 split
__global__ void split_kernel(const float* __restrict__ src, u16* __restrict__ hi,
                             u16* __restrict__ lo, int n) {
  int i = blockIdx.x * 256 + threadIdx.x;
  if (i >= n) return;
  float v = src[i];
  u16 h = f2bf(v);
  hi[i] = h;
  lo[i] = f2bf(v - bf2f(h));
}
// f32 -> bf16 round only (for Wv: V output is single-bf16 anyway)
__global__ void round_kernel(const float* __restrict__ src, u16* __restrict__ hi, int n) {
  int i = blockIdx.x * 256 + threadIdx.x;
  if (i >= n) return;
  hi[i] = f2bf(src[i]);
}

// Core: C[M,N] = A * B^T with NT split terms, m97-style global_load_lds staging.
// NT==3: (Ah+Al)(Bh+Bl) ~ hh+hl+lh     NT==2: Ah(Bh+Bl)     NT==1: Ah*Bh
// MODE 0: f32 -> Cf ; MODE 1: split bf16 -> (Ch,Cl) ; MODE 2: V^T bf16 -> Ch
//   (MODE 2: [b][h][d][s]: ((row>>11)*16 + col>>7)*128 + (col&127))*2048 + (row&2047))
template <int NT, int MODE>
__device__ __forceinline__ void gemm_core(
    u16* sm, const u16* __restrict__ Ah, const u16* __restrict__ Al,
    const u16* __restrict__ Bh, const u16* __restrict__ Bl,
    float* __restrict__ Cf, u16* __restrict__ Ch, u16* __restrict__ Cl,
    int N, int K, int m0, int n0) {
  u16* sAh = sm;
  u16* sBh = sm + 4096;
  u16* sBl = sm + 8192;   // NT>=2
  u16* sAl = sm + 12288;  // NT==3
  const int tid = threadIdx.x;
  const int w = tid >> 6, lane = tid & 63;
  const int quad = lane >> 4, l16 = lane & 15;
  const int wm = (w >> 1) << 6, wn = (w & 1) << 6;
  const int lrow = lane >> 2, lcol = (lane & 3) << 3;

  f32x4 acc[4][4];
#pragma unroll
  for (int i = 0; i < 4; ++i)
#pragma unroll
    for (int n = 0; n < 4; ++n) acc[i][n] = (f32x4){0.f, 0.f, 0.f, 0.f};

  for (int k0 = 0; k0 < K; k0 += 32) {
    __syncthreads();
#pragma unroll
    for (int j = 0; j < 2; ++j) {
      int r = w * 32 + j * 16 + lrow;
      int lb = (w * 32 + j * 16) * 32;  // wave-uniform LDS base
      size_t ga = (size_t)(m0 + r) * K + k0 + lcol;
      size_t gb = (size_t)(n0 + r) * K + k0 + lcol;
      gload16(Ah + ga, &sAh[lb]);
      gload16(Bh + gb, &sBh[lb]);
      if (NT >= 2) gload16(Bl + gb, &sBl[lb]);
      if (NT == 3) gload16(Al + ga, &sAl[lb]);
    }
    __syncthreads();
    bf16x8 ah[4], al[4], bh[4], bl[4];
#pragma unroll
    for (int i = 0; i < 4; ++i) {
      int o = (wm + i * 16 + l16) * 32 + quad * 8;
      ah[i] = *(const bf16x8*)&sAh[o];
      if (NT == 3) al[i] = *(const bf16x8*)&sAl[o];
    }
#pragma unroll
    for (int n = 0; n < 4; ++n) {
      int o = (wn + n * 16 + l16) * 32 + quad * 8;
      bh[n] = *(const bf16x8*)&sBh[o];
      if (NT >= 2) bl[n] = *(const bf16x8*)&sBl[o];
    }
#pragma unroll
    for (int i = 0; i < 4; ++i)
#pragma unroll
      for (int n = 0; n < 4; ++n) {
        acc[i][n] = __builtin_amdgcn_mfma_f32_16x16x32_bf16(ah[i], bh[n], acc[i][n], 0, 0, 0);
        if (NT >= 2)
          acc[i][n] = __builtin_amdgcn_mfma_f32_16x16x32_bf16(ah[i], bl[n], acc[i][n], 0, 0, 0);
        if (NT == 3)
          acc[i][n] = __builtin_amdgcn_mfma_f32_16x16x32_bf16(al[i], bh[n], acc[i][n], 0, 0, 0);
      }
  }
  // epilogue: C/D layout row=(lane>>4)*4+r, col=lane&15
#pragma unroll
  for (int i = 0; i < 4; ++i)
#pragma unroll
    for (int n = 0; n < 4; ++n) {
      int row0 = m0 + wm + i * 16 + quad * 4;
      int col = n0 + wn + n * 16 + l16;
      if (MODE == 0) {
#pragma unroll
        for (int r = 0; r < 4; ++r) Cf[(size_t)(row0 + r) * N + col] = acc[i][n][r];
      } else if (MODE == 1) {
#pragma unroll
        for (int r = 0; r < 4; ++r) {
          float v = acc[i][n][r];
          size_t o = (size_t)(row0 + r) * N + col;
          u16 h = f2bf(v);
          Ch[o] = h;
          Cl[o] = f2bf(v - bf2f(h));
        }
      } else {
        int brow = row0 >> 11, s0 = row0 & 2047;
        int hh = col >> 7, d = col & 127;
        ushort4 pk;
        pk.x = f2bf(acc[i][n][0]);
        pk.y = f2bf(acc[i][n][1]);
        pk.z = f2bf(acc[i][n][2]);
        pk.w = f2bf(acc[i][n][3]);
        *(ushort4*)(Ch + ((size_t)(brow * 16 + hh) * 128 + d) * 2048 + s0) = pk;
      }
    }
}

// Fused QKV projection: grid (16, 32, 3); z selects Q / K (3-term, split out)
// or V (1-term, V^T out).
__global__ __launch_bounds__(256) void qkv_kernel(
    const u16* __restrict__ xh, const u16* __restrict__ xl,
    const u16* __restrict__ Wqh, const u16* __restrict__ Wql,
    const u16* __restrict__ Wkh, const u16* __restrict__ Wkl,
    const u16* __restrict__ Wvh,
    u16* qh, u16* ql, u16* kh, u16* kl, u16* vt) {
  __shared__ u16 sm[4 * 4096];
  const int m0 = blockIdx.y << 7, n0 = blockIdx.x << 7;
  if (blockIdx.z == 0)
    gemm_core<3, 1>(sm, xh, xl, Wqh, Wql, nullptr, qh, ql, DMODEL, DMODEL, m0, n0);
  else if (blockIdx.z == 1)
    gemm_core<3, 1>(sm, xh, xl, Wkh, Wkl, nullptr, kh, kl, DMODEL, DMODEL, m0, n0);
  else
    gemm_core<1, 2>(sm, xh, nullptr, Wvh, nullptr, nullptr, vt, nullptr, DMODEL, DMODEL, m0, n0);
}

// out = ch * (Woh + Wol)^T  (2-term; ctx-lo dropped -> ~1e-3 RMS, negligible)
__global__ __launch_bounds__(256) void out_kernel(
    const u16* __restrict__ ch, const u16* __restrict__ Woh,
    const u16* __restrict__ Wol, float* __restrict__ out) {
  __shared__ u16 sm[3 * 4096];
  gemm_core<2, 0>(sm, ch, nullptr, Woh, Wol, out, nullptr, nullptr, DMODEL, DMODEL,
                  blockIdx.y << 7, blockIdx.x << 7);
}

// RoPE on split q,k in place (vectorized x4); q pre-scaled by sqrt(128)
// (the reference MULTIPLIES scores by sqrt(128)).
__global__ void rope_split(u16* __restrict__ qh, u16* __restrict__ ql,
                           u16* __restrict__ kh, u16* __restrict__ kl,
                           const float* __restrict__ cosT, const float* __restrict__ sinT) {
  int idx = blockIdx.x * 256 + threadIdx.x;  // [isk][b][s][hh][t]
  int t   = idx & 15;
  int hh  = (idx >> 4) & 15;
  int s   = (idx >> 8) & 2047;
  int b   = (idx >> 19) & 1;
  int isk = (idx >> 20) & 1;
  u16* th = isk ? kh : qh;
  u16* tl = isk ? kl : ql;
  size_t base = (size_t)(b * 2048 + s) * DMODEL + hh * 128 + t * 4;
  float4 c4 = *(const float4*)&cosT[s * 128 + t * 4];
  float4 s4 = *(const float4*)&sinT[s * 128 + t * 4];
  ushort4 h1 = *(ushort4*)&th[base], h2 = *(ushort4*)&th[base + 64];
  ushort4 lo1 = *(ushort4*)&tl[base], lo2 = *(ushort4*)&tl[base + 64];
  float c[4] = {c4.x, c4.y, c4.z, c4.w};
  float sn[4] = {s4.x, s4.y, s4.z, s4.w};
  u16 x1h[4] = {h1.x, h1.y, h1.z, h1.w}, x2h[4] = {h2.x, h2.y, h2.z, h2.w};
  u16 x1l[4] = {lo1.x, lo1.y, lo1.z, lo1.w}, x2l[4] = {lo2.x, lo2.y, lo2.z, lo2.w};
  u16 o1h[4], o1l[4], o2h[4], o2l[4];
  const float qs = 11.313708498984761f;  // sqrt(128)
#pragma unroll
  for (int e = 0; e < 4; ++e) {
    float x1 = bf2f(x1h[e]) + bf2f(x1l[e]);
    float x2 = bf2f(x2h[e]) + bf2f(x2l[e]);
    float o1 = x1 * c[e] - x2 * sn[e];
    float o2 = x2 * c[e] + x1 * sn[e];
    if (!isk) { o1 *= qs; o2 *= qs; }
    o1h[e] = f2bf(o1); o1l[e] = f2bf(o1 - bf2f(o1h[e]));
    o2h[e] = f2bf(o2); o2l[e] = f2bf(o2 - bf2f(o2h[e]));
  }
  *(ushort4*)&th[base]      = (ushort4){o1h[0], o1h[1], o1h[2], o1h[3]};
  *(ushort4*)&tl[base]      = (ushort4){o1l[0], o1l[1], o1l[2], o1l[3]};
  *(ushort4*)&th[base + 64] = (ushort4){o2h[0], o2h[1], o2h[2], o2h[3]};
  *(ushort4*)&tl[base + 64] = (ushort4){o2l[0], o2l[1], o2l[2], o2l[3]};
}

// Flash attention, causal. q pre-scaled by sqrt(128). 3-term split QK^T,
// f32 online softmax, single-bf16 PV with V^T staged from [b][h][d][s].
// P round-trip buffer aliased into sKl (extra barrier after QK) -> 53.2 KB LDS
// -> 3 blocks/CU. Register prefetch of tile kt+1. qt descending. ctx hi-only out.
__global__ __launch_bounds__(256) void attn3_kernel(
    const u16* __restrict__ Qh, const u16* __restrict__ Ql,
    const u16* __restrict__ Kh, const u16* __restrict__ Kl,
    const u16* __restrict__ VT, u16* __restrict__ Ch) {
  const int qt = gridDim.x - 1 - blockIdx.x;  // big blocks first
  const int bh = blockIdx.y;
  const int b = bh >> 4, h = bh & 15;
  const int tid = threadIdx.x;
  const int w = tid >> 6, lane = tid & 63;
  const int quad = lane >> 4, l16 = lane & 15;

  __shared__ u16 sKh[64 * 136];   // K hi, rows padded 128->136
  __shared__ u16 sKlP[64 * 136];  // K lo; after QK-barrier reused as per-wave P
  __shared__ u16 sVt[128 * 72];   // V^T tile [d][k], rows padded 64->72
  u16* sP = &sKlP[w * 1152];      // per-wave 16 x 72

  const size_t bhbase = (size_t)b * S_CTX * DMODEL + (size_t)h * 128;
  const size_t vtbase = (size_t)bh * 128 * 2048;

  int kr[4], kc[4], vr[4], vc[4];
#pragma unroll
  for (int j = 0; j < 4; ++j) {
    int c = j * 256 + tid;
    kr[j] = c >> 4; kc[j] = (c & 15) << 3;
    vr[j] = c >> 3; vc[j] = (c & 7) << 3;
  }

  // Q fragments; wave w owns q-rows qt*64+w*16+[0,16)
  const int qrow = qt * 64 + w * 16 + l16;
  const size_t qoff = bhbase + (size_t)qrow * DMODEL;
  bf16x8 qfh[4], qfl[4];
#pragma unroll
  for (int c = 0; c < 4; ++c) {
    qfh[c] = *(const bf16x8*)(Qh + qoff + c * 32 + quad * 8);
    qfl[c] = *(const bf16x8*)(Ql + qoff + c * 32 + quad * 8);
  }

  f32x4 oacc[8];
#pragma unroll
  for (int d = 0; d < 8; ++d) oacc[d] = (f32x4){0.f, 0.f, 0.f, 0.f};
  float m_r[4] = {-INFINITY, -INFINITY, -INFINITY, -INFINITY};
  float l_r[4] = {0.f, 0.f, 0.f, 0.f};

  bf16x8 rkh[4], rkl[4], rvt[4];
#pragma unroll
  for (int j = 0; j < 4; ++j) {
    size_t g = bhbase + (size_t)kr[j] * DMODEL + kc[j];
    rkh[j] = *(const bf16x8*)(Kh + g);
    rkl[j] = *(const bf16x8*)(Kl + g);
    rvt[j] = *(const bf16x8*)(VT + vtbase + (size_t)vr[j] * 2048 + vc[j]);
  }

  for (int kt = 0; kt <= qt; ++kt) {
    __syncthreads();  // (1) prev iter LDS reads done
#pragma unroll
    for (int j = 0; j < 4; ++j) {
      *(bf16x8*)&sKh[kr[j] * 136 + kc[j]] = rkh[j];
      *(bf16x8*)&sKlP[kr[j] * 136 + kc[j]] = rkl[j];
      *(bf16x8*)&sVt[vr[j] * 72 + vc[j]] = rvt[j];
    }
    __syncthreads();  // (2) tiles visible
    if (kt < qt) {
#pragma unroll
      for (int j = 0; j < 4; ++j) {
        size_t g = bhbase + (size_t)((kt + 1) * 64 + kr[j]) * DMODEL + kc[j];
        rkh[j] = *(const bf16x8*)(Kh + g);
        rkl[j] = *(const bf16x8*)(Kl + g);
        rvt[j] = *(const bf16x8*)(VT + vtbase + (size_t)vr[j] * 2048 + (kt + 1) * 64 + vc[j]);
      }
    }

    // S = Q.K^T, 3-term split
    f32x4 sacc[4];
#pragma unroll
    for (int n = 0; n < 4; ++n) sacc[n] = (f32x4){0.f, 0.f, 0.f, 0.f};
#pragma unroll
    for (int n = 0; n < 4; ++n)
#pragma unroll
      for (int c = 0; c < 4; ++c) {
        int o = (n * 16 + l16) * 136 + c * 32 + quad * 8;
        bf16x8 kfh = *(const bf16x8*)&sKh[o];
        bf16x8 kfl = *(const bf16x8*)&sKlP[o];
        sacc[n] = __builtin_amdgcn_mfma_f32_16x16x32_bf16(qfh[c], kfh, sacc[n], 0, 0, 0);
        sacc[n] = __builtin_amdgcn_mfma_f32_16x16x32_bf16(qfh[c], kfl, sacc[n], 0, 0, 0);
        sacc[n] = __builtin_amdgcn_mfma_f32_16x16x32_bf16(qfl[c], kfh, sacc[n], 0, 0, 0);
      }
    __syncthreads();  // (3) all waves done reading K-lo; its space becomes P

    float pm[4][4];
    float rowmax[4] = {-INFINITY, -INFINITY, -INFINITY, -INFINITY};
#pragma unroll
    for (int n = 0; n < 4; ++n)
#pragma unroll
      for (int r = 0; r < 4; ++r) {
        float sc = sacc[n][r];
        if (kt == qt) {
          int qi = w * 16 + quad * 4 + r;
          int ki = n * 16 + l16;
          if (ki > qi) sc = -INFINITY;
        }
        pm[n][r] = sc;
        rowmax[r] = fmaxf(rowmax[r], sc);
      }
#pragma unroll
    for (int off = 1; off < 16; off <<= 1)
#pragma unroll
      for (int r = 0; r < 4; ++r)
        rowmax[r] = fmaxf(rowmax[r], __shfl_xor(rowmax[r], off, 64));

    float alphav[4];
#pragma unroll
    for (int r = 0; r < 4; ++r) {
      float mnew = fmaxf(m_r[r], rowmax[r]);
      alphav[r] = __expf(m_r[r] - mnew);
      m_r[r] = mnew;
      l_r[r] *= alphav[r];
    }
    float rowsum[4] = {0.f, 0.f, 0.f, 0.f};
#pragma unroll
    for (int n = 0; n < 4; ++n)
#pragma unroll
      for (int r = 0; r < 4; ++r) {
        float p = __expf(pm[n][r] - m_r[r]);
        pm[n][r] = p;
        rowsum[r] += p;
      }
#pragma unroll
    for (int off = 1; off < 16; off <<= 1)
#pragma unroll
      for (int r = 0; r < 4; ++r) rowsum[r] += __shfl_xor(rowsum[r], off, 64);
#pragma unroll
    for (int r = 0; r < 4; ++r) l_r[r] += rowsum[r];

#pragma unroll
    for (int d = 0; d < 8; ++d)
#pragma unroll
      for (int r = 0; r < 4; ++r) oacc[d][r] *= alphav[r];

    // P (C-layout) -> LDS -> A-layout; per-wave region inside sKlP
#pragma unroll
    for (int n = 0; n < 4; ++n)
#pragma unroll
      for (int r = 0; r < 4; ++r)
        sP[(quad * 4 + r) * 72 + n * 16 + l16] = f2bf(pm[n][r]);

    // O += P.V
#pragma unroll
    for (int c = 0; c < 2; ++c) {
      bf16x8 pf = *(const bf16x8*)&sP[l16 * 72 + c * 32 + quad * 8];
#pragma unroll
      for (int d = 0; d < 8; ++d) {
        bf16x8 vf = *(const bf16x8*)&sVt[(d * 16 + l16) * 72 + c * 32 + quad * 8];
        oacc[d] = __builtin_amdgcn_mfma_f32_16x16x32_bf16(pf, vf, oacc[d], 0, 0, 0);
      }
    }
  }

  float invl[4];
#pragma unroll
  for (int r = 0; r < 4; ++r) invl[r] = 1.f / l_r[r];
#pragma unroll
  for (int d = 0; d < 8; ++d)
#pragma unroll
    for (int r = 0; r < 4; ++r) {
      int row = qt * 64 + w * 16 + quad * 4 + r;
      Ch[bhbase + (size_t)row * DMODEL + d * 16 + l16] = f2bf(oacc[d][r] * invl[r]);
    }
}

extern "C" void kernel_launch(void* const* d_in, const int* in_sizes, int n_in,
                              void* d_out, int out_size, void* d_ws, size_t ws_size,
                              hipStream_t stream) {
  const float* x    = (const float*)d_in[0];
  const float* Wq   = (const float*)d_in[1];
  const float* Wk   = (const float*)d_in[2];
  const float* Wv   = (const float*)d_in[3];
  const float* Wo   = (const float*)d_in[4];
  const float* cosT = (const float*)d_in[5];
  const float* sinT = (const float*)d_in[6];
  float* out = (float*)d_out;

  const size_t NX = 8388608;   // 2*2048*2048
  const size_t NW = 4194304;   // 2048*2048
  u16* p = (u16*)d_ws;
  u16* xh  = p; p += NX;  u16* xl  = p; p += NX;
  u16* Wqh = p; p += NW;  u16* Wql = p; p += NW;
  u16* Wkh = p; p += NW;  u16* Wkl = p; p += NW;
  u16* Wvh = p; p += NW;
  u16* Woh = p; p += NW;  u16* Wol = p; p += NW;
  u16* qh  = p; p += NX;  u16* ql  = p; p += NX;
  u16* kh  = p; p += NX;  u16* kl  = p; p += NX;
  u16* vt  = p; p += NX;
  u16* ch  = p; p += NX;
  // ~193 MiB of d_ws

  split_kernel<<<NX / 256, 256, 0, stream>>>(x, xh, xl, (int)NX);
  split_kernel<<<NW / 256, 256, 0, stream>>>(Wq, Wqh, Wql, (int)NW);
  split_kernel<<<NW / 256, 256, 0, stream>>>(Wk, Wkh, Wkl, (int)NW);
  round_kernel<<<NW / 256, 256, 0, stream>>>(Wv, Wvh, (int)NW);
  split_kernel<<<NW / 256, 256, 0, stream>>>(Wo, Woh, Wol, (int)NW);

  qkv_kernel<<<dim3(16, 32, 3), 256, 0, stream>>>(xh, xl, Wqh, Wql, Wkh, Wkl, Wvh,
                                                  qh, ql, kh, kl, vt);

  rope_split<<<8192, 256, 0, stream>>>(qh, ql, kh, kl, cosT, sinT);

  attn3_kernel<<<dim3(32, 32), 256, 0, stream>>>(qh, ql, kh, kl, vt, ch);

  out_kernel<<<dim3(16, 32), 256, 0, stream>>>(ch, Woh, Wol, out);
}

// Round 6
// 663.393 us; speedup vs baseline: 1.8256x; 1.1141x over previous
//
#include <hip/hip_runtime.h>

typedef unsigned short u16;
typedef __attribute__((ext_vector_type(8))) _Float16 f16x8;
typedef __attribute__((ext_vector_type(4))) float f32x4;

#define S_CTX 2048
#define DMODEL 2048

__device__ __forceinline__ u16 f2h(float f) {
  _Float16 h = (_Float16)f; u16 u; __builtin_memcpy(&u, &h, 2); return u;
}
__device__ __forceinline__ float h2f(u16 u) {
  _Float16 h; __builtin_memcpy(&h, &u, 2); return (float)h;
}
__device__ __forceinline__ void gload16(const u16* g, u16* l) {
  __builtin_amdgcn_global_load_lds(
      (const __attribute__((address_space(1))) unsigned int*)g,
      (__attribute__((address_space(3))) unsigned int*)l, 16, 0, 0);
}

// One fused split pass. x -> fp16 pair (no scale). Wq,Wk -> fp16 pair (x64).
// Wv,Wo -> fp16 single (x64). Scales folded out downstream (q-prescale, /4096).
__global__ void split_all(const float* __restrict__ x, const float* __restrict__ Wq,
                          const float* __restrict__ Wk, const float* __restrict__ Wv,
                          const float* __restrict__ Wo,
                          u16* xh, u16* xl, u16* Wqh, u16* Wql,
                          u16* Wkh, u16* Wkl, u16* Wvh, u16* Woh) {
  size_t i = (size_t)blockIdx.x * 256 + threadIdx.x;
  const size_t NX = 8388608, NW = 4194304;
  if (i < NX) {
    float v = x[i];
    u16 h = f2h(v);
    xh[i] = h; xl[i] = f2h(v - h2f(h));
  } else {
    size_t j = i - NX;
    int wsel = (int)(j >> 22);
    size_t o = j & (NW - 1);
    if (wsel == 0) { float v = Wq[o] * 64.f; u16 h = f2h(v); Wqh[o] = h; Wql[o] = f2h(v - h2f(h)); }
    else if (wsel == 1) { float v = Wk[o] * 64.f; u16 h = f2h(v); Wkh[o] = h; Wkl[o] = f2h(v - h2f(h)); }
    else if (wsel == 2) { Wvh[o] = f2h(Wv[o] * 64.f); }
    else { Woh[o] = f2h(Wo[o] * 64.f); }
  }
}

// C[M,N] = A * B^T, fp16 MFMA, NT split terms, m97-style global_load_lds staging.
// NT==3: AhBh+AhBl+AlBh   NT==1: AhBh
// MODE 0: f32*oscale -> Cf ; MODE 1: fp16 pair -> (Ch,Cl) ; MODE 2: V^T fp16 -> Ch
template <int NT, int MODE>
__device__ __forceinline__ void gemm_core(
    u16* sm, const u16* __restrict__ Ah, const u16* __restrict__ Al,
    const u16* __restrict__ Bh, const u16* __restrict__ Bl,
    float* __restrict__ Cf, u16* __restrict__ Ch, u16* __restrict__ Cl,
    int N, int K, int m0, int n0, float oscale) {
  u16* sAh = sm;
  u16* sBh = sm + 4096;
  u16* sBl = sm + 8192;   // NT==3
  u16* sAl = sm + 12288;  // NT==3
  const int tid = threadIdx.x;
  const int w = tid >> 6, lane = tid & 63;
  const int quad = lane >> 4, l16 = lane & 15;
  const int wm = (w >> 1) << 6, wn = (w & 1) << 6;
  const int lrow = lane >> 2, lcol = (lane & 3) << 3;

  f32x4 acc[4][4];
#pragma unroll
  for (int i = 0; i < 4; ++i)
#pragma unroll
    for (int n = 0; n < 4; ++n) acc[i][n] = (f32x4){0.f, 0.f, 0.f, 0.f};

  for (int k0 = 0; k0 < K; k0 += 32) {
    __syncthreads();
#pragma unroll
    for (int j = 0; j < 2; ++j) {
      int r = w * 32 + j * 16 + lrow;
      int lb = (w * 32 + j * 16) * 32;  // wave-uniform LDS base
      size_t ga = (size_t)(m0 + r) * K + k0 + lcol;
      size_t gb = (size_t)(n0 + r) * K + k0 + lcol;
      gload16(Ah + ga, &sAh[lb]);
      gload16(Bh + gb, &sBh[lb]);
      if (NT == 3) {
        gload16(Bl + gb, &sBl[lb]);
        gload16(Al + ga, &sAl[lb]);
      }
    }
    __syncthreads();
    f16x8 ah[4], al[4], bh[4], bl[4];
#pragma unroll
    for (int i = 0; i < 4; ++i) {
      int o = (wm + i * 16 + l16) * 32 + quad * 8;
      ah[i] = *(const f16x8*)&sAh[o];
      if (NT == 3) al[i] = *(const f16x8*)&sAl[o];
    }
#pragma unroll
    for (int n = 0; n < 4; ++n) {
      int o = (wn + n * 16 + l16) * 32 + quad * 8;
      bh[n] = *(const f16x8*)&sBh[o];
      if (NT == 3) bl[n] = *(const f16x8*)&sBl[o];
    }
#pragma unroll
    for (int i = 0; i < 4; ++i)
#pragma unroll
      for (int n = 0; n < 4; ++n) {
        acc[i][n] = __builtin_amdgcn_mfma_f32_16x16x32_f16(ah[i], bh[n], acc[i][n], 0, 0, 0);
        if (NT == 3) {
          acc[i][n] = __builtin_amdgcn_mfma_f32_16x16x32_f16(ah[i], bl[n], acc[i][n], 0, 0, 0);
          acc[i][n] = __builtin_amdgcn_mfma_f32_16x16x32_f16(al[i], bh[n], acc[i][n], 0, 0, 0);
        }
      }
  }
  // epilogue: C/D layout row=(lane>>4)*4+r, col=lane&15
#pragma unroll
  for (int i = 0; i < 4; ++i)
#pragma unroll
    for (int n = 0; n < 4; ++n) {
      int row0 = m0 + wm + i * 16 + quad * 4;
      int col = n0 + wn + n * 16 + l16;
      if (MODE == 0) {
#pragma unroll
        for (int r = 0; r < 4; ++r) Cf[(size_t)(row0 + r) * N + col] = acc[i][n][r] * oscale;
      } else if (MODE == 1) {
#pragma unroll
        for (int r = 0; r < 4; ++r) {
          float v = acc[i][n][r];
          size_t o = (size_t)(row0 + r) * N + col;
          u16 h = f2h(v);
          Ch[o] = h;
          Cl[o] = f2h(v - h2f(h));
        }
      } else {
        int brow = row0 >> 11, s0 = row0 & 2047;
        int hh = col >> 7, d = col & 127;
        ushort4 pk;
        pk.x = f2h(acc[i][n][0]);
        pk.y = f2h(acc[i][n][1]);
        pk.z = f2h(acc[i][n][2]);
        pk.w = f2h(acc[i][n][3]);
        *(ushort4*)(Ch + ((size_t)(brow * 16 + hh) * 128 + d) * 2048 + s0) = pk;
      }
    }
}

// Fused QKV projection: grid (16, 32, 3); z: Q / K (3-term, pair out), V (1-term, V^T out)
__global__ __launch_bounds__(256) void qkv_kernel(
    const u16* __restrict__ xh, const u16* __restrict__ xl,
    const u16* __restrict__ Wqh, const u16* __restrict__ Wql,
    const u16* __restrict__ Wkh, const u16* __restrict__ Wkl,
    const u16* __restrict__ Wvh,
    u16* qh, u16* ql, u16* kh, u16* kl, u16* vt) {
  __shared__ u16 sm[4 * 4096];
  const int m0 = blockIdx.y << 7, n0 = blockIdx.x << 7;
  if (blockIdx.z == 0)
    gemm_core<3, 1>(sm, xh, xl, Wqh, Wql, nullptr, qh, ql, DMODEL, DMODEL, m0, n0, 1.f);
  else if (blockIdx.z == 1)
    gemm_core<3, 1>(sm, xh, xl, Wkh, Wkl, nullptr, kh, kl, DMODEL, DMODEL, m0, n0, 1.f);
  else
    gemm_core<1, 2>(sm, xh, nullptr, Wvh, nullptr, nullptr, vt, nullptr, DMODEL, DMODEL, m0, n0, 1.f);
}

// out = (ch * Woh^T) / 4096  (1-term fp16; dropped terms ~1.5e-4)
__global__ __launch_bounds__(256) void out_kernel(
    const u16* __restrict__ ch, const u16* __restrict__ Woh, float* __restrict__ out) {
  __shared__ u16 sm[2 * 4096];
  gemm_core<1, 0>(sm, ch, nullptr, Woh, nullptr, out, nullptr, nullptr, DMODEL, DMODEL,
                  blockIdx.y << 7, blockIdx.x << 7, 1.f / 4096.f);
}

// RoPE: read fp16 pairs (exact), rotate in f32, write SINGLE fp16.
// q additionally scaled by sqrt(128)/4096 (reference multiplies scores by
// sqrt(128); /4096 compensates the x64 weight scaling on both q and k).
__global__ void rope_f16(u16* __restrict__ qh, const u16* __restrict__ ql,
                         u16* __restrict__ kh, const u16* __restrict__ kl,
                         const float* __restrict__ cosT, const float* __restrict__ sinT) {
  int idx = blockIdx.x * 256 + threadIdx.x;  // [isk][b][s][hh][t]
  int t   = idx & 15;
  int hh  = (idx >> 4) & 15;
  int s   = (idx >> 8) & 2047;
  int b   = (idx >> 19) & 1;
  int isk = (idx >> 20) & 1;
  u16* th = isk ? kh : qh;
  const u16* tl = isk ? kl : ql;
  size_t base = (size_t)(b * 2048 + s) * DMODEL + hh * 128 + t * 4;
  float4 c4 = *(const float4*)&cosT[s * 128 + t * 4];
  float4 s4 = *(const float4*)&sinT[s * 128 + t * 4];
  ushort4 h1 = *(ushort4*)&th[base], h2 = *(ushort4*)&th[base + 64];
  ushort4 lo1 = *(const ushort4*)&tl[base], lo2 = *(const ushort4*)&tl[base + 64];
  float c[4] = {c4.x, c4.y, c4.z, c4.w};
  float sn[4] = {s4.x, s4.y, s4.z, s4.w};
  u16 x1h[4] = {h1.x, h1.y, h1.z, h1.w}, x2h[4] = {h2.x, h2.y, h2.z, h2.w};
  u16 x1l[4] = {lo1.x, lo1.y, lo1.z, lo1.w}, x2l[4] = {lo2.x, lo2.y, lo2.z, lo2.w};
  u16 o1[4], o2[4];
  const float qs = 0.002762135864009951f;  // sqrt(128)/4096
#pragma unroll
  for (int e = 0; e < 4; ++e) {
    float x1 = h2f(x1h[e]) + h2f(x1l[e]);
    float x2 = h2f(x2h[e]) + h2f(x2l[e]);
    float r1 = x1 * c[e] - x2 * sn[e];
    float r2 = x2 * c[e] + x1 * sn[e];
    if (!isk) { r1 *= qs; r2 *= qs; }
    o1[e] = f2h(r1);
    o2[e] = f2h(r2);
  }
  *(ushort4*)&th[base]      = (ushort4){o1[0], o1[1], o1[2], o1[3]};
  *(ushort4*)&th[base + 64] = (ushort4){o2[0], o2[1], o2[2], o2[3]};
}

// Flash attention, causal. 1-term fp16 QK (q pre-scaled), f32 online softmax,
// fp16 P and PV with V^T [b][h][d][s]. BQ=128: 512 thr = 8 waves x 16 q-rows
// sharing K/V tiles (BK=64). P in its OWN per-wave LDS buffer (no aliasing,
// no barrier needed for it: strictly within-wave write->read). 2 barriers/iter.
// Register prefetch of tile kt+1; qt descending; ch = 64*ctx fp16.
__global__ __launch_bounds__(512) void attn_kernel(
    const u16* __restrict__ Qh, const u16* __restrict__ Kh,
    const u16* __restrict__ VT, u16* __restrict__ Ch) {
  const int qt = gridDim.x - 1 - blockIdx.x;  // big blocks first
  const int bh = blockIdx.y;
  const int b = bh >> 4, h = bh & 15;
  const int tid = threadIdx.x;
  const int w = tid >> 6, lane = tid & 63;
  const int quad = lane >> 4, l16 = lane & 15;

  __shared__ u16 sKh[64 * 136];   // K-tile [k][d] pitch 136
  __shared__ u16 sVt[128 * 72];   // V^T tile [d][k], pitch 72
  __shared__ u16 sPb[8 * 1088];   // per-wave P, 16 x 68 each (dedicated)
  u16* sP = &sPb[w * 1088];

  const size_t bhbase = (size_t)b * S_CTX * DMODEL + (size_t)h * 128;
  const size_t vtbase = (size_t)bh * 128 * 2048;

  int kr[2], kc[2], vr[2], vc[2];
#pragma unroll
  for (int j = 0; j < 2; ++j) {
    int c = j * 512 + tid;
    kr[j] = c >> 4; kc[j] = (c & 15) << 3;
    vr[j] = c >> 3; vc[j] = (c & 7) << 3;
  }

  // Q fragments; wave w owns q-rows qt*128 + w*16 + [0,16)
  const int qr0 = qt * 128 + w * 16;
  const size_t qoff = bhbase + (size_t)(qr0 + l16) * DMODEL;
  f16x8 qf[4];
#pragma unroll
  for (int c = 0; c < 4; ++c) qf[c] = *(const f16x8*)(Qh + qoff + c * 32 + quad * 8);

  f32x4 oacc[8];
#pragma unroll
  for (int d = 0; d < 8; ++d) oacc[d] = (f32x4){0.f, 0.f, 0.f, 0.f};
  float m_r[4] = {-INFINITY, -INFINITY, -INFINITY, -INFINITY};
  float l_r[4] = {0.f, 0.f, 0.f, 0.f};

  f16x8 rkh[2], rvt[2];
#pragma unroll
  for (int j = 0; j < 2; ++j) {
    rkh[j] = *(const f16x8*)(Kh + bhbase + (size_t)kr[j] * DMODEL + kc[j]);
    rvt[j] = *(const f16x8*)(VT + vtbase + (size_t)vr[j] * 2048 + vc[j]);
  }

  const int nkt = 2 * qt + 2;
  for (int kt = 0; kt < nkt; ++kt) {
    __syncthreads();  // (1) prev iter QK/PV reads of sKh/sVt done
#pragma unroll
    for (int j = 0; j < 2; ++j) {
      *(f16x8*)&sKh[kr[j] * 136 + kc[j]] = rkh[j];
      *(f16x8*)&sVt[vr[j] * 72 + vc[j]] = rvt[j];
    }
    __syncthreads();  // (2) tiles visible
    if (kt + 1 < nkt) {
#pragma unroll
      for (int j = 0; j < 2; ++j) {
        size_t g = bhbase + (size_t)((kt + 1) * 64 + kr[j]) * DMODEL + kc[j];
        rkh[j] = *(const f16x8*)(Kh + g);
        rvt[j] = *(const f16x8*)(VT + vtbase + (size_t)vr[j] * 2048 + (kt + 1) * 64 + vc[j]);
      }
    }

    const bool active = (kt * 64) <= (qr0 + 15);
    if (active) {
      f32x4 sacc[4];
#pragma unroll
      for (int n = 0; n < 4; ++n) sacc[n] = (f32x4){0.f, 0.f, 0.f, 0.f};
#pragma unroll
      for (int n = 0; n < 4; ++n)
#pragma unroll
        for (int c = 0; c < 4; ++c) {
          f16x8 kf = *(const f16x8*)&sKh[(n * 16 + l16) * 136 + c * 32 + quad * 8];
          sacc[n] = __builtin_amdgcn_mfma_f32_16x16x32_f16(qf[c], kf, sacc[n], 0, 0, 0);
        }

      float pm[4][4];
      float rowmax[4] = {-INFINITY, -INFINITY, -INFINITY, -INFINITY};
#pragma unroll
      for (int n = 0; n < 4; ++n)
#pragma unroll
        for (int r = 0; r < 4; ++r) {
          float sc = sacc[n][r];
          int qi = qr0 + quad * 4 + r;
          int ki = kt * 64 + n * 16 + l16;
          if (ki > qi) sc = -INFINITY;
          pm[n][r] = sc;
          rowmax[r] = fmaxf(rowmax[r], sc);
        }
#pragma unroll
      for (int off = 1; off < 16; off <<= 1)
#pragma unroll
        for (int r = 0; r < 4; ++r)
          rowmax[r] = fmaxf(rowmax[r], __shfl_xor(rowmax[r], off, 64));

      float alphav[4];
#pragma unroll
      for (int r = 0; r < 4; ++r) {
        float mnew = fmaxf(m_r[r], rowmax[r]);
        alphav[r] = __expf(m_r[r] - mnew);
        m_r[r] = mnew;
        l_r[r] *= alphav[r];
      }
      float rowsum[4] = {0.f, 0.f, 0.f, 0.f};
#pragma unroll
      for (int n = 0; n < 4; ++n)
#pragma unroll
        for (int r = 0; r < 4; ++r) {
          float p = __expf(pm[n][r] - m_r[r]);
          pm[n][r] = p;
          rowsum[r] += p;
        }
#pragma unroll
      for (int off = 1; off < 16; off <<= 1)
#pragma unroll
        for (int r = 0; r < 4; ++r) rowsum[r] += __shfl_xor(rowsum[r], off, 64);
#pragma unroll
      for (int r = 0; r < 4; ++r) l_r[r] += rowsum[r];

#pragma unroll
      for (int d = 0; d < 8; ++d)
#pragma unroll
        for (int r = 0; r < 4; ++r) oacc[d][r] *= alphav[r];

      // P (C-layout) -> per-wave dedicated LDS region -> A-layout
#pragma unroll
      for (int n = 0; n < 4; ++n)
#pragma unroll
        for (int r = 0; r < 4; ++r)
          sP[(quad * 4 + r) * 68 + n * 16 + l16] = f2h(pm[n][r]);

      // O += P.V
#pragma unroll
      for (int c = 0; c < 2; ++c) {
        f16x8 pf = *(const f16x8*)&sP[l16 * 68 + c * 32 + quad * 8];
#pragma unroll
        for (int d = 0; d < 8; ++d) {
          f16x8 vf = *(const f16x8*)&sVt[(d * 16 + l16) * 72 + c * 32 + quad * 8];
          oacc[d] = __builtin_amdgcn_mfma_f32_16x16x32_f16(pf, vf, oacc[d], 0, 0, 0);
        }
      }
    }
  }

  float invl[4];
#pragma unroll
  for (int r = 0; r < 4; ++r) invl[r] = 1.f / l_r[r];
#pragma unroll
  for (int d = 0; d < 8; ++d)
#pragma unroll
    for (int r = 0; r < 4; ++r) {
      int row = qr0 + quad * 4 + r;
      Ch[bhbase + (size_t)row * DMODEL + d * 16 + l16] = f2h(oacc[d][r] * invl[r]);
    }
}

extern "C" void kernel_launch(void* const* d_in, const int* in_sizes, int n_in,
                              void* d_out, int out_size, void* d_ws, size_t ws_size,
                              hipStream_t stream) {
  const float* x    = (const float*)d_in[0];
  const float* Wq   = (const float*)d_in[1];
  const float* Wk   = (const float*)d_in[2];
  const float* Wv   = (const float*)d_in[3];
  const float* Wo   = (const float*)d_in[4];
  const float* cosT = (const float*)d_in[5];
  const float* sinT = (const float*)d_in[6];
  float* out = (float*)d_out;

  const size_t NX = 8388608;   // 2*2048*2048
  const size_t NW = 4194304;   // 2048*2048
  u16* p = (u16*)d_ws;
  u16* xh  = p; p += NX;  u16* xl  = p; p += NX;
  u16* Wqh = p; p += NW;  u16* Wql = p; p += NW;
  u16* Wkh = p; p += NW;  u16* Wkl = p; p += NW;
  u16* Wvh = p; p += NW;  u16* Woh = p; p += NW;
  u16* qh  = p; p += NX;  u16* ql  = p; p += NX;
  u16* kh  = p; p += NX;  u16* kl  = p; p += NX;
  u16* vt  = p; p += NX;
  u16* ch  = p; p += NX;
  // ~184 MiB of d_ws

  split_all<<<98304, 256, 0, stream>>>(x, Wq, Wk, Wv, Wo,
                                       xh, xl, Wqh, Wql, Wkh, Wkl, Wvh, Woh);

  qkv_kernel<<<dim3(16, 32, 3), 256, 0, stream>>>(xh, xl, Wqh, Wql, Wkh, Wkl, Wvh,
                                                  qh, ql, kh, kl, vt);

  rope_f16<<<8192, 256, 0, stream>>>(qh, ql, kh, kl, cosT, sinT);

  attn_kernel<<<dim3(16, 32), 512, 0, stream>>>(qh, kh, vt, ch);

  out_kernel<<<dim3(16, 32), 256, 0, stream>>>(ch, Woh, out);
}